// Round 13
// baseline (57.942 us; speedup 1.0000x reference)
//
#include <hip/hip_runtime.h>

#define NV 1084
#define NVPAD 1088
#define NPART 64   // precompute partials
#define NBATCH 8   // batches per joints block

typedef __attribute__((ext_vector_type(8))) short short8v;
typedef __attribute__((ext_vector_type(4))) float f32x4;

__device__ inline unsigned short f2bf(float f) {
    unsigned int u = __float_as_uint(f);
    unsigned int r = (u + 0x7FFFu + ((u >> 16) & 1u)) >> 16;
    return (unsigned short)r;
}

// ws layout:
//  wsA    : B*192 f32          A_rel [B][16][12]
//  Mpart  : NPART*1392 f32     partials: M[21][16][4] (1344) + jt[48]
//  Mfinal : 1344 f32
//  Gbf    : NVPAD*64 ushort    G[v][4k+d] = w[v][k]*{vx,vy,vz,1}[d]  (bf16)
//  Abf    : 3B*64 ushort       Abf[3b+p][4k+d] = A_rel[b][k][4p+d]   (bf16)

__device__ inline void rodrigues9(float x, float y, float z, float R[9]) {
    float n2 = x * x + y * y + z * z + 1e-8f;
    float angle = sqrtf(n2);
    float inv = 1.0f / angle;
    float ax = x * inv, ay = y * inv, az = z * inv;
    float c = cosf(angle), s = sinf(angle);
    float C = 1.0f - c;
    R[0] = 1.0f - C * (ay * ay + az * az);
    R[1] = -s * az + C * ax * ay;
    R[2] = s * ay + C * ax * az;
    R[3] = s * az + C * ax * ay;
    R[4] = 1.0f - C * (ax * ax + az * az);
    R[5] = -s * ax + C * ay * az;
    R[6] = -s * ay + C * ax * az;
    R[7] = s * ax + C * ay * az;
    R[8] = 1.0f - C * (ax * ax + ay * ay);
}

// K1: blocks [0,NPART): partial M/jt over 17 verts each.
//     blocks [NPART,NPART+nG): Gbf table (bf16), one element per thread.
__global__ __launch_bounds__(384) void prep_kernel(
    const float* __restrict__ vt, const float* __restrict__ jreg,
    const float* __restrict__ wts, float* __restrict__ Mpart,
    unsigned short* __restrict__ Gbf) {
    int blk = blockIdx.x;
    int t = threadIdx.x;
    if (blk < NPART) {
        int p = blk;
        int v0 = p * 17, v1 = min(v0 + 17, NV);
        float* mp = Mpart + (size_t)p * 1392;
        if (t < 336) {
            int j = t >> 4, k = t & 15;
            float m0 = 0.f, m1 = 0.f, m2 = 0.f, s = 0.f;
            for (int v = v0; v < v1; ++v) {
                float jw = jreg[v * 21 + j] * wts[v * 16 + k];
                m0 += jw * vt[v * 3 + 0];
                m1 += jw * vt[v * 3 + 1];
                m2 += jw * vt[v * 3 + 2];
                s += jw;
            }
            mp[t * 4 + 0] = m0;
            mp[t * 4 + 1] = m1;
            mp[t * 4 + 2] = m2;
            mp[t * 4 + 3] = s;
        } else if (t < 384) {
            int o = t - 336;
            int j = o / 3, c = o - j * 3;
            float acc = 0.f;
            for (int v = v0; v < v1; ++v) acc += vt[v * 3 + c] * jreg[v * 21 + j];
            mp[1344 + o] = acc;
        }
    } else {
        int idx = (blk - NPART) * 384 + t;
        if (idx < NVPAD * 64) {
            int v = idx >> 6, i = idx & 63;
            int k = i >> 2, d = i & 3;
            float val = 0.f;
            if (v < NV) {
                float vh = (d == 3) ? 1.f : vt[v * 3 + d];
                val = wts[v * 16 + k] * vh;
            }
            Gbf[idx] = f2bf(val);
        }
    }
}

// K2: blocks [0, nFK): FK per (batch, chain-role), euler inline; writes both
//     f32 A_rel (for joints) and bf16 Abf rows (for the MFMA GEMM).
//     blocks [nFK, nFK+21): lane-parallel reduce of M-partials into Mfinal.
__global__ __launch_bounds__(256) void fk_kernel(
    const float* __restrict__ theta, const float* __restrict__ wrist,
    const float* __restrict__ hc, const float* __restrict__ hm,
    const float* __restrict__ Mpart, float* __restrict__ wsA,
    float* __restrict__ Mfinal, unsigned short* __restrict__ Abf,
    int total, int nFK) {
    int blk = blockIdx.x;
    int t = threadIdx.x;
    if (blk >= nFK) {
        __shared__ float sm[256];
        int q = (blk - nFK) * 64 + (t & 63);
        int pg = t >> 6;
        float acc = 0.f;
#pragma unroll
        for (int u = 0; u < 16; ++u) acc += Mpart[(size_t)(pg * 16 + u) * 1392 + q];
        sm[t] = acc;
        __syncthreads();
        if (pg == 0) Mfinal[q] = sm[t] + sm[t + 64] + sm[t + 128] + sm[t + 192];
        return;
    }
    __shared__ float sred[192];
    __shared__ float sj[48];
    if (t < 192) {
        int g = t / 48, o = t - g * 48;
        float acc = 0.f;
#pragma unroll
        for (int u = 0; u < 16; ++u)
            acc += Mpart[(size_t)(g * 16 + u) * 1392 + 1344 + o];
        sred[t] = acc;
    }
    __syncthreads();
    if (t < 48) sj[t] = sred[t] + sred[48 + t] + sred[96 + t] + sred[144 + t];
    __syncthreads();

    int idx = blk * 256 + t;
    if (idx >= total) return;  // total = B*5
    int b = idx / 5, r = idx - b * 5;

    float e[9];
    {
        const float* th = theta + (size_t)b * 45;
        int base = 9 * r;
#pragma unroll
        for (int col = 0; col < 9; ++col) e[col] = hm[base + col];
        for (int k = 0; k < 45; ++k) {
            float tk = th[k];
            const float* hck = hc + k * 45 + base;
#pragma unroll
            for (int col = 0; col < 9; ++col) e[col] += tk * hck[col];
        }
    }

    float R[9];
    rodrigues9(wrist[b * 3 + 0], wrist[b * 3 + 1], wrist[b * 3 + 2], R);
    float J0x = sj[0], J0y = sj[1], J0z = sj[2];
    float Ap[12];
    Ap[0] = R[0]; Ap[1] = R[1]; Ap[2] = R[2]; Ap[3] = J0x;
    Ap[4] = R[3]; Ap[5] = R[4]; Ap[6] = R[5]; Ap[7] = J0y;
    Ap[8] = R[6]; Ap[9] = R[7]; Ap[10] = R[8]; Ap[11] = J0z;
    float* out = wsA + (size_t)b * 192;
    if (r == 0) {
#pragma unroll
        for (int row = 0; row < 3; ++row) {
            float a0 = Ap[row * 4 + 0], a1 = Ap[row * 4 + 1], a2 = Ap[row * 4 + 2];
            float a3 = Ap[row * 4 + 3] - (a0 * J0x + a1 * J0y + a2 * J0z);
            out[row * 4 + 0] = a0;
            out[row * 4 + 1] = a1;
            out[row * 4 + 2] = a2;
            out[row * 4 + 3] = a3;
            ushort4 h;
            h.x = f2bf(a0); h.y = f2bf(a1); h.z = f2bf(a2); h.w = f2bf(a3);
            *(ushort4*)(Abf + (size_t)(3 * b + row) * 64) = h;
        }
    }
    float px = J0x, py = J0y, pz = J0z;
#pragma unroll
    for (int s = 0; s < 3; ++s) {
        int i = r * 3 + s + 1;
        rodrigues9(e[3 * s + 0], e[3 * s + 1], e[3 * s + 2], R);
        float jx = sj[i * 3 + 0], jy = sj[i * 3 + 1], jz = sj[i * 3 + 2];
        float tx = jx - px, ty = jy - py, tz = jz - pz;
        float An[12];
#pragma unroll
        for (int row = 0; row < 3; ++row) {
            An[row * 4 + 0] = Ap[row * 4 + 0] * R[0] + Ap[row * 4 + 1] * R[3] + Ap[row * 4 + 2] * R[6];
            An[row * 4 + 1] = Ap[row * 4 + 0] * R[1] + Ap[row * 4 + 1] * R[4] + Ap[row * 4 + 2] * R[7];
            An[row * 4 + 2] = Ap[row * 4 + 0] * R[2] + Ap[row * 4 + 1] * R[5] + Ap[row * 4 + 2] * R[8];
            An[row * 4 + 3] = Ap[row * 4 + 3] + Ap[row * 4 + 0] * tx + Ap[row * 4 + 1] * ty + Ap[row * 4 + 2] * tz;
        }
        float* oi = out + i * 12;
#pragma unroll
        for (int row = 0; row < 3; ++row) {
            float a0 = An[row * 4 + 0], a1 = An[row * 4 + 1], a2 = An[row * 4 + 2];
            float a3 = An[row * 4 + 3] - (a0 * jx + a1 * jy + a2 * jz);
            oi[row * 4 + 0] = a0;
            oi[row * 4 + 1] = a1;
            oi[row * 4 + 2] = a2;
            oi[row * 4 + 3] = a3;
            ushort4 h;
            h.x = f2bf(a0); h.y = f2bf(a1); h.z = f2bf(a2); h.w = f2bf(a3);
            *(ushort4*)(Abf + (size_t)(3 * b + row) * 64 + 4 * i) = h;
        }
#pragma unroll
        for (int q = 0; q < 12; ++q) Ap[q] = An[q];
        px = jx; py = jy; pz = jz;
    }
}

// K3: blocks [0, nVB): MFMA GEMM with LDS-transposed coalesced stores.
//   Block = 16 batches (48 m-rows) x 64 verts. Wave w owns v-tile w (16 v),
//   computes 3 m-subtiles (B-frag loaded once, 6 MFMA), writes C to LDS
//   [48][65]; then 256 threads store [16 b][64 v][3 p] as coalesced float4.
// blocks [nVB, nVB + B/NBATCH): joints (f32 path) for NBATCH batches each.
__global__ __launch_bounds__(256) void verts_joints_kernel(
    const float* __restrict__ wsA, const float* __restrict__ Mfinal,
    const unsigned short* __restrict__ Abf, const unsigned short* __restrict__ Gbf,
    float* __restrict__ verts, float* __restrict__ jout, int nVB) {
    int bid = blockIdx.x;
    int t = threadIdx.x;

    if (bid < nVB) {
        __shared__ float sC[48 * 65];
        int Mgrp = bid / 17;            // 16-batch group
        int vt4 = bid - Mgrp * 17;      // 64-vert tile
        int v0 = vt4 * 64;
        int b0 = Mgrp * 16;
        int w = t >> 6, lane = t & 63;
        int lrow = lane & 15, lk = lane >> 4;

        // B-frag for this wave's 16-vert column tile (zero-padded past NV)
        int v = v0 + w * 16 + lrow;
        const unsigned short* Br = Gbf + (size_t)v * 64 + lk * 8;
        short8v g0 = *(const short8v*)Br;
        short8v g1 = *(const short8v*)(Br + 32);

#pragma unroll
        for (int msub = 0; msub < 3; ++msub) {
            const unsigned short* Ar =
                Abf + (size_t)(Mgrp * 48 + msub * 16 + lrow) * 64 + lk * 8;
            short8v a0 = *(const short8v*)Ar;
            short8v a1 = *(const short8v*)(Ar + 32);
            f32x4 acc = {0.f, 0.f, 0.f, 0.f};
            acc = __builtin_amdgcn_mfma_f32_16x16x32_bf16(a0, g0, acc, 0, 0, 0);
            acc = __builtin_amdgcn_mfma_f32_16x16x32_bf16(a1, g1, acc, 0, 0, 0);
            // C: row = lk*4+q (m within subtile), col = lrow (v within tile)
            float* dst = &sC[(msub * 16 + lk * 4) * 65 + w * 16 + lrow];
#pragma unroll
            for (int q = 0; q < 4; ++q) dst[q * 65] = acc[q];
        }
        __syncthreads();

        // store: batch bl gets 192 contiguous floats verts[b0+bl][v0..v0+63][:]
        if (v0 + 64 <= NV) {
#pragma unroll
            for (int i = 0; i < 3; ++i) {
                int f = t + 256 * i;            // 0..767 float4 index
                int bl = f / 48, r = f - bl * 48;
                int off = r * 4;
                float4 val;
                {
                    int o0 = off + 0, v_ = o0 / 3, p_ = o0 - v_ * 3;
                    val.x = sC[(bl * 3 + p_) * 65 + v_];
                }
                {
                    int o1 = off + 1, v_ = o1 / 3, p_ = o1 - v_ * 3;
                    val.y = sC[(bl * 3 + p_) * 65 + v_];
                }
                {
                    int o2 = off + 2, v_ = o2 / 3, p_ = o2 - v_ * 3;
                    val.z = sC[(bl * 3 + p_) * 65 + v_];
                }
                {
                    int o3 = off + 3, v_ = o3 / 3, p_ = o3 - v_ * 3;
                    val.w = sC[(bl * 3 + p_) * 65 + v_];
                }
                *(float4*)(verts + (size_t)(b0 + bl) * (NV * 3) + v0 * 3 + off) = val;
            }
        } else {
            int nf = (NV - v0) * 3;             // 180 valid floats per batch
            for (int e = t; e < 16 * nf; e += 256) {
                int bl = e / nf, o = e - bl * nf;
                int v_ = o / 3, p_ = o - v_ * 3;
                verts[(size_t)(b0 + bl) * (NV * 3) + v0 * 3 + o] =
                    sC[(bl * 3 + p_) * 65 + v_];
            }
        }
    } else {
        // joints: jout[b, j, c] = sum_k sum_d M[j][k][d] * A[b][k][c*4+d]
        int b0 = (bid - nVB) * NBATCH;
        for (int o = t; o < NBATCH * 63; o += 256) {
            int bl = o / 63;
            int rem = o - bl * 63;
            int j = rem / 3;
            int c = rem - j * 3;
            const float* A = wsA + (size_t)(b0 + bl) * 192 + c * 4;
            const float* Mj = Mfinal + j * 64;
            float acc = 0.f;
#pragma unroll
            for (int k = 0; k < 16; ++k) {
                float4 av = *(const float4*)&A[k * 12];
                float4 m = *(const float4*)&Mj[k * 4];
                acc += av.x * m.x + av.y * m.y + av.z * m.z + av.w * m.w;
            }
            jout[(size_t)(b0 + bl) * 63 + rem] = acc;
        }
    }
}

extern "C" void kernel_launch(void* const* d_in, const int* in_sizes, int n_in,
                              void* d_out, int out_size, void* d_ws, size_t ws_size,
                              hipStream_t stream) {
    const float* theta = (const float*)d_in[1];
    const float* wrist = (const float*)d_in[2];
    const float* vtpl  = (const float*)d_in[3];
    const float* jreg  = (const float*)d_in[4];
    const float* hc    = (const float*)d_in[5];
    const float* hm    = (const float*)d_in[6];
    const float* wts   = (const float*)d_in[7];
    int B = in_sizes[1] / 45;  // 4096

    float* ws     = (float*)d_ws;
    float* wsA    = ws;                            // B*192 f32
    float* Mpart  = ws + (size_t)B * 192;          // NPART*1392 f32
    float* Mfinal = Mpart + (size_t)NPART * 1392;  // 1344 f32
    unsigned short* Gbf = (unsigned short*)(Mfinal + 1344);  // NVPAD*64 ushort
    unsigned short* Abf = Gbf + (size_t)NVPAD * 64;          // 3B*64 ushort
    float* verts  = (float*)d_out;
    float* jout   = verts + (size_t)B * NV * 3;

    int nG = (NVPAD * 64 + 383) / 384;             // 182
    prep_kernel<<<NPART + nG, 384, 0, stream>>>(vtpl, jreg, wts, Mpart, Gbf);
    int nFK = (B * 5 + 255) / 256;
    fk_kernel<<<nFK + 21, 256, 0, stream>>>(theta, wrist, hc, hm, Mpart, wsA,
                                            Mfinal, Abf, B * 5, nFK);
    int nVB = ((3 * B) / 48) * 17;                 // 4352 for B=4096
    verts_joints_kernel<<<nVB + B / NBATCH, 256, 0, stream>>>(
        wsA, Mfinal, Abf, Gbf, verts, jout, nVB);
}

// Round 15
// 52.648 us; speedup vs baseline: 1.1006x; 1.1006x over previous
//
#include <hip/hip_runtime.h>

#define NV 1084
#define NVPAD 1088
#define NPART 64   // precompute partials
#define NBATCH 8   // batches per joints block

typedef __attribute__((ext_vector_type(8))) short short8v;
typedef __attribute__((ext_vector_type(4))) float f32x4;

__device__ inline unsigned short f2bf(float f) {
    unsigned int u = __float_as_uint(f);
    unsigned int r = (u + 0x7FFFu + ((u >> 16) & 1u)) >> 16;
    return (unsigned short)r;
}

// ws layout:
//  wsA    : B*192 f32          A_rel [B][16][12]
//  Mpart  : NPART*1392 f32     partials: M[21][16][4] (1344) + jt[48]
//  Mfinal : 1344 f32
//  Gbf    : NVPAD*64 ushort    G[v][4k+d] = w[v][k]*{vx,vy,vz,1}[d]  (bf16)
//  Abf    : 3B*64 ushort       Abf[3b+p][4k+d] = A_rel[b][k][4p+d]   (bf16)

__device__ inline void rodrigues9(float x, float y, float z, float R[9]) {
    float n2 = x * x + y * y + z * z + 1e-8f;
    float angle = sqrtf(n2);
    float inv = 1.0f / angle;
    float ax = x * inv, ay = y * inv, az = z * inv;
    float c = cosf(angle), s = sinf(angle);
    float C = 1.0f - c;
    R[0] = 1.0f - C * (ay * ay + az * az);
    R[1] = -s * az + C * ax * ay;
    R[2] = s * ay + C * ax * az;
    R[3] = s * az + C * ax * ay;
    R[4] = 1.0f - C * (ax * ax + az * az);
    R[5] = -s * ax + C * ay * az;
    R[6] = -s * ay + C * ax * az;
    R[7] = s * ax + C * ay * az;
    R[8] = 1.0f - C * (ax * ax + ay * ay);
}

// K1: blocks [0,NPART): partial M/jt over 17 verts each.
//     blocks [NPART,NPART+nG): Gbf table (bf16), one element per thread.
__global__ __launch_bounds__(384) void prep_kernel(
    const float* __restrict__ vt, const float* __restrict__ jreg,
    const float* __restrict__ wts, float* __restrict__ Mpart,
    unsigned short* __restrict__ Gbf) {
    int blk = blockIdx.x;
    int t = threadIdx.x;
    if (blk < NPART) {
        int p = blk;
        int v0 = p * 17, v1 = min(v0 + 17, NV);
        float* mp = Mpart + (size_t)p * 1392;
        if (t < 336) {
            int j = t >> 4, k = t & 15;
            float m0 = 0.f, m1 = 0.f, m2 = 0.f, s = 0.f;
            for (int v = v0; v < v1; ++v) {
                float jw = jreg[v * 21 + j] * wts[v * 16 + k];
                m0 += jw * vt[v * 3 + 0];
                m1 += jw * vt[v * 3 + 1];
                m2 += jw * vt[v * 3 + 2];
                s += jw;
            }
            mp[t * 4 + 0] = m0;
            mp[t * 4 + 1] = m1;
            mp[t * 4 + 2] = m2;
            mp[t * 4 + 3] = s;
        } else if (t < 384) {
            int o = t - 336;
            int j = o / 3, c = o - j * 3;
            float acc = 0.f;
            for (int v = v0; v < v1; ++v) acc += vt[v * 3 + c] * jreg[v * 21 + j];
            mp[1344 + o] = acc;
        }
    } else {
        int idx = (blk - NPART) * 384 + t;
        if (idx < NVPAD * 64) {
            int v = idx >> 6, i = idx & 63;
            int k = i >> 2, d = i & 3;
            float val = 0.f;
            if (v < NV) {
                float vh = (d == 3) ? 1.f : vt[v * 3 + d];
                val = wts[v * 16 + k] * vh;
            }
            Gbf[idx] = f2bf(val);
        }
    }
}

// K2: blocks [0, nFK): FK per (batch, chain-role), euler inline; writes both
//     f32 A_rel (for joints) and bf16 Abf rows (for the MFMA GEMM).
//     blocks [nFK, nFK+21): lane-parallel reduce of M-partials into Mfinal.
__global__ __launch_bounds__(256) void fk_kernel(
    const float* __restrict__ theta, const float* __restrict__ wrist,
    const float* __restrict__ hc, const float* __restrict__ hm,
    const float* __restrict__ Mpart, float* __restrict__ wsA,
    float* __restrict__ Mfinal, unsigned short* __restrict__ Abf,
    int total, int nFK) {
    int blk = blockIdx.x;
    int t = threadIdx.x;
    if (blk >= nFK) {
        __shared__ float sm[256];
        int q = (blk - nFK) * 64 + (t & 63);
        int pg = t >> 6;
        float acc = 0.f;
#pragma unroll
        for (int u = 0; u < 16; ++u) acc += Mpart[(size_t)(pg * 16 + u) * 1392 + q];
        sm[t] = acc;
        __syncthreads();
        if (pg == 0) Mfinal[q] = sm[t] + sm[t + 64] + sm[t + 128] + sm[t + 192];
        return;
    }
    __shared__ float sred[192];
    __shared__ float sj[48];
    if (t < 192) {
        int g = t / 48, o = t - g * 48;
        float acc = 0.f;
#pragma unroll
        for (int u = 0; u < 16; ++u)
            acc += Mpart[(size_t)(g * 16 + u) * 1392 + 1344 + o];
        sred[t] = acc;
    }
    __syncthreads();
    if (t < 48) sj[t] = sred[t] + sred[48 + t] + sred[96 + t] + sred[144 + t];
    __syncthreads();

    int idx = blk * 256 + t;
    if (idx >= total) return;  // total = B*5
    int b = idx / 5, r = idx - b * 5;

    float e[9];
    {
        const float* th = theta + (size_t)b * 45;
        int base = 9 * r;
#pragma unroll
        for (int col = 0; col < 9; ++col) e[col] = hm[base + col];
        for (int k = 0; k < 45; ++k) {
            float tk = th[k];
            const float* hck = hc + k * 45 + base;
#pragma unroll
            for (int col = 0; col < 9; ++col) e[col] += tk * hck[col];
        }
    }

    float R[9];
    rodrigues9(wrist[b * 3 + 0], wrist[b * 3 + 1], wrist[b * 3 + 2], R);
    float J0x = sj[0], J0y = sj[1], J0z = sj[2];
    float Ap[12];
    Ap[0] = R[0]; Ap[1] = R[1]; Ap[2] = R[2]; Ap[3] = J0x;
    Ap[4] = R[3]; Ap[5] = R[4]; Ap[6] = R[5]; Ap[7] = J0y;
    Ap[8] = R[6]; Ap[9] = R[7]; Ap[10] = R[8]; Ap[11] = J0z;
    float* out = wsA + (size_t)b * 192;
    if (r == 0) {
#pragma unroll
        for (int row = 0; row < 3; ++row) {
            float a0 = Ap[row * 4 + 0], a1 = Ap[row * 4 + 1], a2 = Ap[row * 4 + 2];
            float a3 = Ap[row * 4 + 3] - (a0 * J0x + a1 * J0y + a2 * J0z);
            out[row * 4 + 0] = a0;
            out[row * 4 + 1] = a1;
            out[row * 4 + 2] = a2;
            out[row * 4 + 3] = a3;
            ushort4 h;
            h.x = f2bf(a0); h.y = f2bf(a1); h.z = f2bf(a2); h.w = f2bf(a3);
            *(ushort4*)(Abf + (size_t)(3 * b + row) * 64) = h;
        }
    }
    float px = J0x, py = J0y, pz = J0z;
#pragma unroll
    for (int s = 0; s < 3; ++s) {
        int i = r * 3 + s + 1;
        rodrigues9(e[3 * s + 0], e[3 * s + 1], e[3 * s + 2], R);
        float jx = sj[i * 3 + 0], jy = sj[i * 3 + 1], jz = sj[i * 3 + 2];
        float tx = jx - px, ty = jy - py, tz = jz - pz;
        float An[12];
#pragma unroll
        for (int row = 0; row < 3; ++row) {
            An[row * 4 + 0] = Ap[row * 4 + 0] * R[0] + Ap[row * 4 + 1] * R[3] + Ap[row * 4 + 2] * R[6];
            An[row * 4 + 1] = Ap[row * 4 + 0] * R[1] + Ap[row * 4 + 1] * R[4] + Ap[row * 4 + 2] * R[7];
            An[row * 4 + 2] = Ap[row * 4 + 0] * R[2] + Ap[row * 4 + 1] * R[5] + Ap[row * 4 + 2] * R[8];
            An[row * 4 + 3] = Ap[row * 4 + 3] + Ap[row * 4 + 0] * tx + Ap[row * 4 + 1] * ty + Ap[row * 4 + 2] * tz;
        }
        float* oi = out + i * 12;
#pragma unroll
        for (int row = 0; row < 3; ++row) {
            float a0 = An[row * 4 + 0], a1 = An[row * 4 + 1], a2 = An[row * 4 + 2];
            float a3 = An[row * 4 + 3] - (a0 * jx + a1 * jy + a2 * jz);
            oi[row * 4 + 0] = a0;
            oi[row * 4 + 1] = a1;
            oi[row * 4 + 2] = a2;
            oi[row * 4 + 3] = a3;
            ushort4 h;
            h.x = f2bf(a0); h.y = f2bf(a1); h.z = f2bf(a2); h.w = f2bf(a3);
            *(ushort4*)(Abf + (size_t)(3 * b + row) * 64 + 4 * i) = h;
        }
#pragma unroll
        for (int q = 0; q < 12; ++q) Ap[q] = An[q];
        px = jx; py = jy; pz = jz;
    }
}

// K3: blocks [0, nVB): MFMA GEMM with LDS-transposed stores; verts/jout
//   written NON-TEMPORALLY (bypass L2 dirty residency — write-once data).
// blocks [nVB, nVB + B/NBATCH): joints (f32 path) for NBATCH batches each.
__global__ __launch_bounds__(256) void verts_joints_kernel(
    const float* __restrict__ wsA, const float* __restrict__ Mfinal,
    const unsigned short* __restrict__ Abf, const unsigned short* __restrict__ Gbf,
    float* __restrict__ verts, float* __restrict__ jout, int nVB) {
    int bid = blockIdx.x;
    int t = threadIdx.x;

    if (bid < nVB) {
        __shared__ float sC[48 * 65];
        int Mgrp = bid / 17;            // 16-batch group
        int vt4 = bid - Mgrp * 17;      // 64-vert tile
        int v0 = vt4 * 64;
        int b0 = Mgrp * 16;
        int w = t >> 6, lane = t & 63;
        int lrow = lane & 15, lk = lane >> 4;

        // B-frag for this wave's 16-vert column tile (zero-padded past NV)
        int v = v0 + w * 16 + lrow;
        const unsigned short* Br = Gbf + (size_t)v * 64 + lk * 8;
        short8v g0 = *(const short8v*)Br;
        short8v g1 = *(const short8v*)(Br + 32);

#pragma unroll
        for (int msub = 0; msub < 3; ++msub) {
            const unsigned short* Ar =
                Abf + (size_t)(Mgrp * 48 + msub * 16 + lrow) * 64 + lk * 8;
            short8v a0 = *(const short8v*)Ar;
            short8v a1 = *(const short8v*)(Ar + 32);
            f32x4 acc = {0.f, 0.f, 0.f, 0.f};
            acc = __builtin_amdgcn_mfma_f32_16x16x32_bf16(a0, g0, acc, 0, 0, 0);
            acc = __builtin_amdgcn_mfma_f32_16x16x32_bf16(a1, g1, acc, 0, 0, 0);
            // C: row = lk*4+q (m within subtile), col = lrow (v within tile)
            float* dst = &sC[(msub * 16 + lk * 4) * 65 + w * 16 + lrow];
#pragma unroll
            for (int q = 0; q < 4; ++q) dst[q * 65] = acc[q];
        }
        __syncthreads();

        // store: batch bl gets 192 contiguous floats verts[b0+bl][v0..v0+63][:]
        if (v0 + 64 <= NV) {
#pragma unroll
            for (int i = 0; i < 3; ++i) {
                int f = t + 256 * i;            // 0..767 float4 index
                int bl = f / 48, r = f - bl * 48;
                int off = r * 4;
                f32x4 val;
                {
                    int o0 = off + 0, v_ = o0 / 3, p_ = o0 - v_ * 3;
                    val.x = sC[(bl * 3 + p_) * 65 + v_];
                }
                {
                    int o1 = off + 1, v_ = o1 / 3, p_ = o1 - v_ * 3;
                    val.y = sC[(bl * 3 + p_) * 65 + v_];
                }
                {
                    int o2 = off + 2, v_ = o2 / 3, p_ = o2 - v_ * 3;
                    val.z = sC[(bl * 3 + p_) * 65 + v_];
                }
                {
                    int o3 = off + 3, v_ = o3 / 3, p_ = o3 - v_ * 3;
                    val.w = sC[(bl * 3 + p_) * 65 + v_];
                }
                __builtin_nontemporal_store(
                    val, (f32x4*)(verts + (size_t)(b0 + bl) * (NV * 3) + v0 * 3 + off));
            }
        } else {
            int nf = (NV - v0) * 3;             // 180 valid floats per batch
            for (int e = t; e < 16 * nf; e += 256) {
                int bl = e / nf, o = e - bl * nf;
                int v_ = o / 3, p_ = o - v_ * 3;
                __builtin_nontemporal_store(
                    sC[(bl * 3 + p_) * 65 + v_],
                    verts + (size_t)(b0 + bl) * (NV * 3) + v0 * 3 + o);
            }
        }
    } else {
        // joints: jout[b, j, c] = sum_k sum_d M[j][k][d] * A[b][k][c*4+d]
        int b0 = (bid - nVB) * NBATCH;
        for (int o = t; o < NBATCH * 63; o += 256) {
            int bl = o / 63;
            int rem = o - bl * 63;
            int j = rem / 3;
            int c = rem - j * 3;
            const float* A = wsA + (size_t)(b0 + bl) * 192 + c * 4;
            const float* Mj = Mfinal + j * 64;
            float acc = 0.f;
#pragma unroll
            for (int k = 0; k < 16; ++k) {
                float4 av = *(const float4*)&A[k * 12];
                float4 m = *(const float4*)&Mj[k * 4];
                acc += av.x * m.x + av.y * m.y + av.z * m.z + av.w * m.w;
            }
            __builtin_nontemporal_store(acc, jout + (size_t)(b0 + bl) * 63 + rem);
        }
    }
}

extern "C" void kernel_launch(void* const* d_in, const int* in_sizes, int n_in,
                              void* d_out, int out_size, void* d_ws, size_t ws_size,
                              hipStream_t stream) {
    const float* theta = (const float*)d_in[1];
    const float* wrist = (const float*)d_in[2];
    const float* vtpl  = (const float*)d_in[3];
    const float* jreg  = (const float*)d_in[4];
    const float* hc    = (const float*)d_in[5];
    const float* hm    = (const float*)d_in[6];
    const float* wts   = (const float*)d_in[7];
    int B = in_sizes[1] / 45;  // 4096

    float* ws     = (float*)d_ws;
    float* wsA    = ws;                            // B*192 f32
    float* Mpart  = ws + (size_t)B * 192;          // NPART*1392 f32
    float* Mfinal = Mpart + (size_t)NPART * 1392;  // 1344 f32
    unsigned short* Gbf = (unsigned short*)(Mfinal + 1344);  // NVPAD*64 ushort
    unsigned short* Abf = Gbf + (size_t)NVPAD * 64;          // 3B*64 ushort
    float* verts  = (float*)d_out;
    float* jout   = verts + (size_t)B * NV * 3;

    int nG = (NVPAD * 64 + 383) / 384;             // 182
    prep_kernel<<<NPART + nG, 384, 0, stream>>>(vtpl, jreg, wts, Mpart, Gbf);
    int nFK = (B * 5 + 255) / 256;
    fk_kernel<<<nFK + 21, 256, 0, stream>>>(theta, wrist, hc, hm, Mpart, wsA,
                                            Mfinal, Abf, B * 5, nFK);
    int nVB = ((3 * B) / 48) * 17;                 // 4352 for B=4096
    verts_joints_kernel<<<nVB + B / NBATCH, 256, 0, stream>>>(
        wsA, Mfinal, Abf, Gbf, verts, jout, nVB);
}

// Round 16
// 51.844 us; speedup vs baseline: 1.1176x; 1.0155x over previous
//
#include <hip/hip_runtime.h>

#define NV 1084
#define NVPAD 1088
#define NPART 64   // precompute partials
#define NBATCH 8   // batches per joints block

typedef __attribute__((ext_vector_type(8))) short short8v;
typedef __attribute__((ext_vector_type(4))) float f32x4;

__device__ inline unsigned short f2bf(float f) {
    unsigned int u = __float_as_uint(f);
    unsigned int r = (u + 0x7FFFu + ((u >> 16) & 1u)) >> 16;
    return (unsigned short)r;
}

// ws layout:
//  wsA    : B*192 f32          A_rel [B][16][12]
//  Mpart  : NPART*1392 f32     partials: M[21][16][4] (1344) + jt[48]
//  Mfinal : 1344 f32
//  Gbf    : NVPAD*64 ushort    G[v][4k+d] = w[v][k]*{vx,vy,vz,1}[d]  (bf16)
//  Abf    : (3B+16)*64 ushort  Abf[3b+p][4k+d] = A_rel[b][k][4p+d]   (bf16)
//                              (+16 pad rows: M-tile reads 4 rows past end)

__device__ inline void rodrigues9(float x, float y, float z, float R[9]) {
    float n2 = x * x + y * y + z * z + 1e-8f;
    float angle = sqrtf(n2);
    float inv = 1.0f / angle;
    float ax = x * inv, ay = y * inv, az = z * inv;
    float c = cosf(angle), s = sinf(angle);
    float C = 1.0f - c;
    R[0] = 1.0f - C * (ay * ay + az * az);
    R[1] = -s * az + C * ax * ay;
    R[2] = s * ay + C * ax * az;
    R[3] = s * az + C * ax * ay;
    R[4] = 1.0f - C * (ax * ax + az * az);
    R[5] = -s * ax + C * ay * az;
    R[6] = -s * ay + C * ax * az;
    R[7] = s * ax + C * ay * az;
    R[8] = 1.0f - C * (ax * ax + ay * ay);
}

// K1: blocks [0,NPART): partial M/jt over 17 verts each.
//     blocks [NPART,NPART+nG): Gbf table (bf16), one element per thread.
__global__ __launch_bounds__(384) void prep_kernel(
    const float* __restrict__ vt, const float* __restrict__ jreg,
    const float* __restrict__ wts, float* __restrict__ Mpart,
    unsigned short* __restrict__ Gbf) {
    int blk = blockIdx.x;
    int t = threadIdx.x;
    if (blk < NPART) {
        int p = blk;
        int v0 = p * 17, v1 = min(v0 + 17, NV);
        float* mp = Mpart + (size_t)p * 1392;
        if (t < 336) {
            int j = t >> 4, k = t & 15;
            float m0 = 0.f, m1 = 0.f, m2 = 0.f, s = 0.f;
            for (int v = v0; v < v1; ++v) {
                float jw = jreg[v * 21 + j] * wts[v * 16 + k];
                m0 += jw * vt[v * 3 + 0];
                m1 += jw * vt[v * 3 + 1];
                m2 += jw * vt[v * 3 + 2];
                s += jw;
            }
            mp[t * 4 + 0] = m0;
            mp[t * 4 + 1] = m1;
            mp[t * 4 + 2] = m2;
            mp[t * 4 + 3] = s;
        } else if (t < 384) {
            int o = t - 336;
            int j = o / 3, c = o - j * 3;
            float acc = 0.f;
            for (int v = v0; v < v1; ++v) acc += vt[v * 3 + c] * jreg[v * 21 + j];
            mp[1344 + o] = acc;
        }
    } else {
        int idx = (blk - NPART) * 384 + t;
        if (idx < NVPAD * 64) {
            int v = idx >> 6, i = idx & 63;
            int k = i >> 2, d = i & 3;
            float val = 0.f;
            if (v < NV) {
                float vh = (d == 3) ? 1.f : vt[v * 3 + d];
                val = wts[v * 16 + k] * vh;
            }
            Gbf[idx] = f2bf(val);
        }
    }
}

// K2: blocks [0, nFK): FK per (batch, chain-role), euler inline; writes both
//     f32 A_rel (for joints) and bf16 Abf rows (for the MFMA GEMM).
//     blocks [nFK, nFK+21): lane-parallel reduce of M-partials into Mfinal.
__global__ __launch_bounds__(256) void fk_kernel(
    const float* __restrict__ theta, const float* __restrict__ wrist,
    const float* __restrict__ hc, const float* __restrict__ hm,
    const float* __restrict__ Mpart, float* __restrict__ wsA,
    float* __restrict__ Mfinal, unsigned short* __restrict__ Abf,
    int total, int nFK) {
    int blk = blockIdx.x;
    int t = threadIdx.x;
    if (blk >= nFK) {
        __shared__ float sm[256];
        int q = (blk - nFK) * 64 + (t & 63);
        int pg = t >> 6;
        float acc = 0.f;
#pragma unroll
        for (int u = 0; u < 16; ++u) acc += Mpart[(size_t)(pg * 16 + u) * 1392 + q];
        sm[t] = acc;
        __syncthreads();
        if (pg == 0) Mfinal[q] = sm[t] + sm[t + 64] + sm[t + 128] + sm[t + 192];
        return;
    }
    __shared__ float sred[192];
    __shared__ float sj[48];
    if (t < 192) {
        int g = t / 48, o = t - g * 48;
        float acc = 0.f;
#pragma unroll
        for (int u = 0; u < 16; ++u)
            acc += Mpart[(size_t)(g * 16 + u) * 1392 + 1344 + o];
        sred[t] = acc;
    }
    __syncthreads();
    if (t < 48) sj[t] = sred[t] + sred[48 + t] + sred[96 + t] + sred[144 + t];
    __syncthreads();

    int idx = blk * 256 + t;
    if (idx >= total) return;  // total = B*5
    int b = idx / 5, r = idx - b * 5;

    float e[9];
    {
        const float* th = theta + (size_t)b * 45;
        int base = 9 * r;
#pragma unroll
        for (int col = 0; col < 9; ++col) e[col] = hm[base + col];
        for (int k = 0; k < 45; ++k) {
            float tk = th[k];
            const float* hck = hc + k * 45 + base;
#pragma unroll
            for (int col = 0; col < 9; ++col) e[col] += tk * hck[col];
        }
    }

    float R[9];
    rodrigues9(wrist[b * 3 + 0], wrist[b * 3 + 1], wrist[b * 3 + 2], R);
    float J0x = sj[0], J0y = sj[1], J0z = sj[2];
    float Ap[12];
    Ap[0] = R[0]; Ap[1] = R[1]; Ap[2] = R[2]; Ap[3] = J0x;
    Ap[4] = R[3]; Ap[5] = R[4]; Ap[6] = R[5]; Ap[7] = J0y;
    Ap[8] = R[6]; Ap[9] = R[7]; Ap[10] = R[8]; Ap[11] = J0z;
    float* out = wsA + (size_t)b * 192;
    if (r == 0) {
#pragma unroll
        for (int row = 0; row < 3; ++row) {
            float a0 = Ap[row * 4 + 0], a1 = Ap[row * 4 + 1], a2 = Ap[row * 4 + 2];
            float a3 = Ap[row * 4 + 3] - (a0 * J0x + a1 * J0y + a2 * J0z);
            out[row * 4 + 0] = a0;
            out[row * 4 + 1] = a1;
            out[row * 4 + 2] = a2;
            out[row * 4 + 3] = a3;
            ushort4 h;
            h.x = f2bf(a0); h.y = f2bf(a1); h.z = f2bf(a2); h.w = f2bf(a3);
            *(ushort4*)(Abf + (size_t)(3 * b + row) * 64) = h;
        }
    }
    float px = J0x, py = J0y, pz = J0z;
#pragma unroll
    for (int s = 0; s < 3; ++s) {
        int i = r * 3 + s + 1;
        rodrigues9(e[3 * s + 0], e[3 * s + 1], e[3 * s + 2], R);
        float jx = sj[i * 3 + 0], jy = sj[i * 3 + 1], jz = sj[i * 3 + 2];
        float tx = jx - px, ty = jy - py, tz = jz - pz;
        float An[12];
#pragma unroll
        for (int row = 0; row < 3; ++row) {
            An[row * 4 + 0] = Ap[row * 4 + 0] * R[0] + Ap[row * 4 + 1] * R[3] + Ap[row * 4 + 2] * R[6];
            An[row * 4 + 1] = Ap[row * 4 + 0] * R[1] + Ap[row * 4 + 1] * R[4] + Ap[row * 4 + 2] * R[7];
            An[row * 4 + 2] = Ap[row * 4 + 0] * R[2] + Ap[row * 4 + 1] * R[5] + Ap[row * 4 + 2] * R[8];
            An[row * 4 + 3] = Ap[row * 4 + 3] + Ap[row * 4 + 0] * tx + Ap[row * 4 + 1] * ty + Ap[row * 4 + 2] * tz;
        }
        float* oi = out + i * 12;
#pragma unroll
        for (int row = 0; row < 3; ++row) {
            float a0 = An[row * 4 + 0], a1 = An[row * 4 + 1], a2 = An[row * 4 + 2];
            float a3 = An[row * 4 + 3] - (a0 * jx + a1 * jy + a2 * jz);
            oi[row * 4 + 0] = a0;
            oi[row * 4 + 1] = a1;
            oi[row * 4 + 2] = a2;
            oi[row * 4 + 3] = a3;
            ushort4 h;
            h.x = f2bf(a0); h.y = f2bf(a1); h.z = f2bf(a2); h.w = f2bf(a3);
            *(ushort4*)(Abf + (size_t)(3 * b + row) * 64 + 4 * i) = h;
        }
#pragma unroll
        for (int q = 0; q < 12; ++q) Ap[q] = An[q];
        px = jx; py = jy; pz = jz;
    }
}

// K3: blocks [0, nVB): MFMA GEMM, one block = 4 consecutive batches (M=12
//   rows in a single 16-row A-tile; rows 12-15 garbage, discarded) x all
//   NVPAD verts. Wave w sweeps v-tiles w, w+4, ... (A-frags in regs),
//   accumulates into LDS [12][1092]; then the block streams out 4 x 3252
//   floats = 52 KB FULLY CONTIGUOUS with NT f32x4 stores (no tail: 3252 =
//   813*4 exactly). Tests the write-locality hypothesis.
// blocks [nVB, nVB + B/NBATCH): joints (f32 path) for NBATCH batches each.
#define SCW 1092
__global__ __launch_bounds__(256) void verts_joints_kernel(
    const float* __restrict__ wsA, const float* __restrict__ Mfinal,
    const unsigned short* __restrict__ Abf, const unsigned short* __restrict__ Gbf,
    float* __restrict__ verts, float* __restrict__ jout, int nVB) {
    int bid = blockIdx.x;
    int t = threadIdx.x;

    if (bid < nVB) {
        __shared__ float sC[12 * SCW];
        int b0 = bid * 4;               // 4 batches
        int w = t >> 6, lane = t & 63;
        int lrow = lane & 15, lk = lane >> 4;

        // A-frags: rows b0*3 + lrow (12 valid; lrow>=12 reads pad, discarded)
        const unsigned short* Ar = Abf + (size_t)(b0 * 3 + lrow) * 64 + lk * 8;
        short8v a0 = *(const short8v*)Ar;
        short8v a1 = *(const short8v*)(Ar + 32);

        for (int vt4 = w; vt4 < NVPAD / 16; vt4 += 4) {
            int v = vt4 * 16 + lrow;
            const unsigned short* Br = Gbf + (size_t)v * 64 + lk * 8;
            short8v g0 = *(const short8v*)Br;
            short8v g1 = *(const short8v*)(Br + 32);
            f32x4 acc = {0.f, 0.f, 0.f, 0.f};
            acc = __builtin_amdgcn_mfma_f32_16x16x32_bf16(a0, g0, acc, 0, 0, 0);
            acc = __builtin_amdgcn_mfma_f32_16x16x32_bf16(a1, g1, acc, 0, 0, 0);
            // C: row = lk*4+q, col = lrow. Keep rows 0-11 (lk<3).
            if (lk < 3) {
                float* dst = &sC[(lk * 4) * SCW + vt4 * 16 + lrow];
#pragma unroll
                for (int q = 0; q < 4; ++q) dst[q * SCW] = acc[q];
            }
        }
        __syncthreads();

        // stream out: 4 batches x 813 f32x4, block-contiguous 52 KB
        float* outp = verts + (size_t)b0 * (NV * 3);
#pragma unroll 1
        for (int f = t; f < 3252; f += 256) {
            int bl = f / 813;
            int off = (f - bl * 813) * 4;
            f32x4 val;
#pragma unroll
            for (int j = 0; j < 4; ++j) {
                int o = off + j;
                int v_ = o / 3, p_ = o - v_ * 3;
                val[j] = sC[(bl * 3 + p_) * SCW + v_];
            }
            __builtin_nontemporal_store(val, (f32x4*)(outp + (size_t)f * 4));
        }
    } else {
        // joints: jout[b, j, c] = sum_k sum_d M[j][k][d] * A[b][k][c*4+d]
        int b0 = (bid - nVB) * NBATCH;
        for (int o = t; o < NBATCH * 63; o += 256) {
            int bl = o / 63;
            int rem = o - bl * 63;
            int j = rem / 3;
            int c = rem - j * 3;
            const float* A = wsA + (size_t)(b0 + bl) * 192 + c * 4;
            const float* Mj = Mfinal + j * 64;
            float acc = 0.f;
#pragma unroll
            for (int k = 0; k < 16; ++k) {
                float4 av = *(const float4*)&A[k * 12];
                float4 m = *(const float4*)&Mj[k * 4];
                acc += av.x * m.x + av.y * m.y + av.z * m.z + av.w * m.w;
            }
            __builtin_nontemporal_store(acc, jout + (size_t)(b0 + bl) * 63 + rem);
        }
    }
}

extern "C" void kernel_launch(void* const* d_in, const int* in_sizes, int n_in,
                              void* d_out, int out_size, void* d_ws, size_t ws_size,
                              hipStream_t stream) {
    const float* theta = (const float*)d_in[1];
    const float* wrist = (const float*)d_in[2];
    const float* vtpl  = (const float*)d_in[3];
    const float* jreg  = (const float*)d_in[4];
    const float* hc    = (const float*)d_in[5];
    const float* hm    = (const float*)d_in[6];
    const float* wts   = (const float*)d_in[7];
    int B = in_sizes[1] / 45;  // 4096

    float* ws     = (float*)d_ws;
    float* wsA    = ws;                            // B*192 f32
    float* Mpart  = ws + (size_t)B * 192;          // NPART*1392 f32
    float* Mfinal = Mpart + (size_t)NPART * 1392;  // 1344 f32
    unsigned short* Gbf = (unsigned short*)(Mfinal + 1344);  // NVPAD*64 ushort
    unsigned short* Abf = Gbf + (size_t)NVPAD * 64;          // (3B+16)*64 ushort
    float* verts  = (float*)d_out;
    float* jout   = verts + (size_t)B * NV * 3;

    int nG = (NVPAD * 64 + 383) / 384;             // 182
    prep_kernel<<<NPART + nG, 384, 0, stream>>>(vtpl, jreg, wts, Mpart, Gbf);
    int nFK = (B * 5 + 255) / 256;
    fk_kernel<<<nFK + 21, 256, 0, stream>>>(theta, wrist, hc, hm, Mpart, wsA,
                                            Mfinal, Abf, B * 5, nFK);
    int nVB = B / 4;                               // 1024 for B=4096
    verts_joints_kernel<<<nVB + B / NBATCH, 256, 0, stream>>>(
        wsA, Mfinal, Abf, Gbf, verts, jout, nVB);
}